// Round 3
// baseline (315.620 us; speedup 1.0000x reference)
//
#include <hip/hip_runtime.h>
#include <math.h>

#define NBINS 28
#define L2E 1.44269504088896340736f

#define EXP2F(x) __builtin_amdgcn_exp2f(x)
#define RCPF(x)  __builtin_amdgcn_rcpf(x)
#define SCHED_FENCE() __builtin_amdgcn_sched_barrier(0)

typedef float v2f __attribute__((ext_vector_type(2)));

static __device__ __forceinline__ v2f splat2(float w) { v2f r; r.x = w; r.y = w; return r; }
static __device__ __forceinline__ v2f make2(float a, float b) { v2f r; r.x = a; r.y = b; return r; }
static __device__ __forceinline__ v2f pkfma(v2f a, v2f b, v2f c) {
    return __builtin_elementwise_fma(a, b, c);
}

// workspace float offsets.  ROW-MAJOR, prescaled:
//   WS_W1[f*16+j] = W1[f][j] * -log2e     (f=0..7,  j=0..15)
//   WS_W2[k*16+j] = W2[k][j] * -log2e     (k=0..15, j=0..15)
// Row-major so each 16-float row is one 64B-aligned s_load_dwordx16:
// weights are wave-uniform -> compiler scalarizes into SGPRs (K$ path).
#define WS_TBL 0    // 40 floats: ml_table[d-1] = exp(ml_mlp(d) - 0.25 d), d=1..40
#define WS_W1  64   // 128 floats, row-major, * -log2e
#define WS_B1  192  // 16, * -log2e
#define WS_W2  208  // 256 floats, row-major, * -log2e
#define WS_B2  464  // 16, * -log2e
#define WS_W3  480  // 16, * +log2e
#define WS_B3  496  // 1, * +log2e
#define WS_TOT 512

__global__ void prep_kernel(const float* __restrict__ mh_W1, const float* __restrict__ mh_b1,
                            const float* __restrict__ mh_W2, const float* __restrict__ mh_b2,
                            const float* __restrict__ mh_W3, const float* __restrict__ mh_b3,
                            const float* __restrict__ ml_W1, const float* __restrict__ ml_b1,
                            const float* __restrict__ ml_W2, const float* __restrict__ ml_b2,
                            const float* __restrict__ ml_W3, const float* __restrict__ ml_b3,
                            float* __restrict__ ws, float* __restrict__ out_bins) {
    const int t = threadIdx.x;  // 64 threads
    for (int k = t; k < 128; k += 64) ws[WS_W1 + k] = -L2E * mh_W1[k];
    for (int k = t; k < 16;  k += 64) ws[WS_B1 + k] = -L2E * mh_b1[k];
    for (int k = t; k < 256; k += 64) ws[WS_W2 + k] = -L2E * mh_W2[k];
    for (int k = t; k < 16;  k += 64) ws[WS_B2 + k] = -L2E * mh_b2[k];
    for (int k = t; k < 16;  k += 64) ws[WS_W3 + k] =  L2E * mh_W3[k];
    if (t == 0) ws[WS_B3] = L2E * mh_b3[0];

    if (t < 40) {
        const float x = (float)(t + 1);
        float h1[16], h2[16];
        #pragma unroll
        for (int j = 0; j < 16; ++j)
            h1[j] = 1.0f / (1.0f + expf(-(x * ml_W1[j] + ml_b1[j])));
        #pragma unroll
        for (int j = 0; j < 16; ++j) {
            float a = ml_b2[j];
            #pragma unroll
            for (int k = 0; k < 16; ++k) a = fmaf(h1[k], ml_W2[k * 16 + j], a);
            h2[j] = 1.0f / (1.0f + expf(-a));
        }
        float phi = ml_b3[0];
        #pragma unroll
        for (int k = 0; k < 16; ++k) phi = fmaf(h2[k], ml_W3[k], phi);
        const float sc = expf(phi - 0.25f * x);
        ws[WS_TBL + t] = sc;
        if (t < NBINS) out_bins[t] = sc;  // dl2_scores term of output 1
    }
}

// 4 rows/thread, rows packed pairwise into v2f so the backend can form
// v_pk_fma_f32 (VOP3P, 2x f32/issue; weight operand is a wave-uniform
// SGPR broadcast via op_sel).  4 rows amortize the 27 wide s_loads over
// 2x the math of the 2-row version, halving the lgkm-stall fraction per
// fence group.  All array indexing compile-time (no scratch).
__global__ __launch_bounds__(256) void main_kernel(
        const float4* __restrict__ x4,
        const int4* __restrict__ dl4p,
        const int4* __restrict__ ml4p,
        const float* __restrict__ ws,
        float4* __restrict__ out4,
        float* __restrict__ out_bins,
        int nquad) {
    __shared__ float s_tbl[40];
    __shared__ float s_bins[4 * NBINS];
    const int tid = threadIdx.x;
    if (tid < 40) s_tbl[tid] = ws[WS_TBL + tid];
    if (tid < 4 * NBINS) s_bins[tid] = 0.0f;
    __syncthreads();

    const int q = blockIdx.x * 256 + tid;
    const bool active = (q < nquad);
    const int qc = active ? q : 0;   // clamp loads; discard via `active` at store

    float xf[4][8];
    #pragma unroll
    for (int r = 0; r < 4; ++r) {
        const float4 a = x4[8 * qc + 2 * r + 0];
        const float4 b = x4[8 * qc + 2 * r + 1];
        xf[r][0] = a.x; xf[r][1] = a.y; xf[r][2] = a.z; xf[r][3] = a.w;
        xf[r][4] = b.x; xf[r][5] = b.y; xf[r][6] = b.z; xf[r][7] = b.w;
    }
    const int4 dl = dl4p[qc];
    const int4 ml = ml4p[qc];

    // ---- layer 1: 8 -> 16 (weights prescaled by -log2e, SGPR-resident) ----
    v2f u01[16], u23[16];
    #pragma unroll
    for (int j = 0; j < 16; ++j) {
        const float b = ws[WS_B1 + j];
        u01[j] = splat2(b); u23[j] = splat2(b);
    }
    SCHED_FENCE();
    #pragma unroll
    for (int f = 0; f < 8; ++f) {
        const v2f x01 = make2(xf[0][f], xf[1][f]);
        const v2f x23 = make2(xf[2][f], xf[3][f]);
        #pragma unroll
        for (int j = 0; j < 16; ++j) {
            const float w = ws[WS_W1 + f * 16 + j];
            const v2f ww = splat2(w);
            u01[j] = pkfma(x01, ww, u01[j]);
            u23[j] = pkfma(x23, ww, u23[j]);
        }
        if (f & 1) SCHED_FENCE();
    }
    v2f h01[16], h23[16];
    #pragma unroll
    for (int j = 0; j < 16; ++j) {
        h01[j] = make2(RCPF(1.0f + EXP2F(u01[j].x)), RCPF(1.0f + EXP2F(u01[j].y)));
        h23[j] = make2(RCPF(1.0f + EXP2F(u23[j].x)), RCPF(1.0f + EXP2F(u23[j].y)));
    }

    // ---- layer 2: 16 -> 16 ----
    v2f v01[16], v23[16];
    #pragma unroll
    for (int j = 0; j < 16; ++j) {
        const float b = ws[WS_B2 + j];
        v01[j] = splat2(b); v23[j] = splat2(b);
    }
    SCHED_FENCE();
    #pragma unroll
    for (int k = 0; k < 16; ++k) {
        #pragma unroll
        for (int j = 0; j < 16; ++j) {
            const float w = ws[WS_W2 + k * 16 + j];
            const v2f ww = splat2(w);
            v01[j] = pkfma(h01[k], ww, v01[j]);
            v23[j] = pkfma(h23[k], ww, v23[j]);
        }
        if (k & 1) SCHED_FENCE();
    }

    // ---- layer 3 + psi ----
    const float pb = ws[WS_B3];          // prescaled by +log2e
    v2f phi01 = splat2(pb), phi23 = splat2(pb);
    #pragma unroll
    for (int j = 0; j < 16; ++j) {
        const float w3 = ws[WS_W3 + j];  // prescaled by +log2e
        const v2f ww = splat2(w3);
        const v2f s01 = make2(RCPF(1.0f + EXP2F(v01[j].x)), RCPF(1.0f + EXP2F(v01[j].y)));
        const v2f s23 = make2(RCPF(1.0f + EXP2F(v23[j].x)), RCPF(1.0f + EXP2F(v23[j].y)));
        phi01 = pkfma(s01, ww, phi01);
        phi23 = pkfma(s23, ww, phi23);
    }
    const float sc0 = EXP2F(fmaf((float)dl.x, -0.25f * L2E, phi01.x));
    const float sc1 = EXP2F(fmaf((float)dl.y, -0.25f * L2E, phi01.y));
    const float sc2 = EXP2F(fmaf((float)dl.z, -0.25f * L2E, phi23.x));
    const float sc3 = EXP2F(fmaf((float)dl.w, -0.25f * L2E, phi23.y));

    // ---- epilogue ----
    if (active) {
        const int i0 = min(max(dl.x, 1), 40) - 1;
        const int i1 = min(max(dl.y, 1), 40) - 1;
        const int i2 = min(max(dl.z, 1), 40) - 1;
        const int i3 = min(max(dl.w, 1), 40) - 1;
        float4 o;
        o.x = sc0 + ((dl.x == ml.x) ? s_tbl[i0] : 0.0f);
        o.y = sc1 + ((dl.y == ml.y) ? s_tbl[i1] : 0.0f);
        o.z = sc2 + ((dl.z == ml.z) ? s_tbl[i2] : 0.0f);
        o.w = sc3 + ((dl.w == ml.w) ? s_tbl[i3] : 0.0f);
        out4[q] = o;
        float* myb = &s_bins[(tid >> 6) * NBINS];
        if (dl.x >= 1 && dl.x <= NBINS) unsafeAtomicAdd(&myb[dl.x - 1], sc0);
        if (dl.y >= 1 && dl.y <= NBINS) unsafeAtomicAdd(&myb[dl.y - 1], sc1);
        if (dl.z >= 1 && dl.z <= NBINS) unsafeAtomicAdd(&myb[dl.z - 1], sc2);
        if (dl.w >= 1 && dl.w <= NBINS) unsafeAtomicAdd(&myb[dl.w - 1], sc3);
    }

    __syncthreads();
    if (tid < NBINS) {
        const float bsum = s_bins[tid] + s_bins[NBINS + tid] +
                           s_bins[2 * NBINS + tid] + s_bins[3 * NBINS + tid];
        unsafeAtomicAdd(&out_bins[tid], bsum);
    }
}

extern "C" void kernel_launch(void* const* d_in, const int* in_sizes, int n_in,
                              void* d_out, int out_size, void* d_ws, size_t ws_size,
                              hipStream_t stream) {
    const int n = in_sizes[0] / 8;  // N rows (N = 4e6, divisible by 4)

    const float* x_feat = (const float*)d_in[0];
    const float* mh_W1  = (const float*)d_in[1];
    const float* mh_b1  = (const float*)d_in[2];
    const float* mh_W2  = (const float*)d_in[3];
    const float* mh_b2  = (const float*)d_in[4];
    const float* mh_W3  = (const float*)d_in[5];
    const float* mh_b3  = (const float*)d_in[6];
    const float* ml_W1  = (const float*)d_in[7];
    const float* ml_b1  = (const float*)d_in[8];
    const float* ml_W2  = (const float*)d_in[9];
    const float* ml_b2  = (const float*)d_in[10];
    const float* ml_W3  = (const float*)d_in[11];
    const float* ml_b3  = (const float*)d_in[12];
    const int* del_lens = (const int*)d_in[13];
    const int* mh_len   = (const int*)d_in[14];

    float* out      = (float*)d_out;
    float* out_bins = out + n;  // last 28 elements of d_out
    float* ws       = (float*)d_ws;

    prep_kernel<<<dim3(1), dim3(64), 0, stream>>>(
        mh_W1, mh_b1, mh_W2, mh_b2, mh_W3, mh_b3,
        ml_W1, ml_b1, ml_W2, ml_b2, ml_W3, ml_b3,
        ws, out_bins);

    const int nquad = n / 4;
    const int nblocks = (nquad + 255) / 256;
    main_kernel<<<dim3(nblocks), dim3(256), 0, stream>>>(
        (const float4*)x_feat, (const int4*)del_lens, (const int4*)mh_len,
        ws, (float4*)out, out_bins, nquad);
}

// Round 5
// 300.751 us; speedup vs baseline: 1.0494x; 1.0494x over previous
//
#include <hip/hip_runtime.h>
#include <math.h>

#define NBINS 28
#define L2E 1.44269504088896340736f

#define EXP2F(x) __builtin_amdgcn_exp2f(x)
#define RCPF(x)  __builtin_amdgcn_rcpf(x)
#define SCHED_FENCE() __builtin_amdgcn_sched_barrier(0)

// workspace float offsets.  ROW-MAJOR, prescaled (proven R1 layout, 512 floats):
//   WS_W1[f*16+j] = W1[f][j] * -log2e     (f=0..7,  j=0..15)
//   WS_W2[k*16+j] = W2[k][j] * -log2e     (k=0..15, j=0..15)
// Weights are wave-uniform -> compiler scalarizes these loads into SGPRs
// (s_load_dwordx16 via K$), zero DS traffic, FMA uses the free SGPR slot.
#define WS_TBL 0    // 40 floats: ml_table[d-1] = exp(ml_mlp(d) - 0.25 d), d=1..40
#define WS_W1  64   // 128 floats, row-major, * -log2e
#define WS_B1  192  // 16, * -log2e
#define WS_W2  208  // 256 floats, row-major, * -log2e
#define WS_B2  464  // 16, * -log2e
#define WS_W3  480  // 16, * +log2e
#define WS_B3  496  // 1, * +log2e
#define WS_TOT 512

__global__ void prep_kernel(const float* __restrict__ mh_W1, const float* __restrict__ mh_b1,
                            const float* __restrict__ mh_W2, const float* __restrict__ mh_b2,
                            const float* __restrict__ mh_W3, const float* __restrict__ mh_b3,
                            const float* __restrict__ ml_W1, const float* __restrict__ ml_b1,
                            const float* __restrict__ ml_W2, const float* __restrict__ ml_b2,
                            const float* __restrict__ ml_W3, const float* __restrict__ ml_b3,
                            float* __restrict__ ws, float* __restrict__ out_bins) {
    const int t = threadIdx.x;  // 64 threads
    for (int k = t; k < 128; k += 64) ws[WS_W1 + k] = -L2E * mh_W1[k];
    for (int k = t; k < 16;  k += 64) ws[WS_B1 + k] = -L2E * mh_b1[k];
    for (int k = t; k < 256; k += 64) ws[WS_W2 + k] = -L2E * mh_W2[k];
    for (int k = t; k < 16;  k += 64) ws[WS_B2 + k] = -L2E * mh_b2[k];
    for (int k = t; k < 16;  k += 64) ws[WS_W3 + k] =  L2E * mh_W3[k];
    if (t == 0) ws[WS_B3] = L2E * mh_b3[0];

    if (t < 40) {
        const float x = (float)(t + 1);
        float h1[16], h2[16];
        #pragma unroll
        for (int j = 0; j < 16; ++j)
            h1[j] = 1.0f / (1.0f + expf(-(x * ml_W1[j] + ml_b1[j])));
        #pragma unroll
        for (int j = 0; j < 16; ++j) {
            float a = ml_b2[j];
            #pragma unroll
            for (int k = 0; k < 16; ++k) a = fmaf(h1[k], ml_W2[k * 16 + j], a);
            h2[j] = 1.0f / (1.0f + expf(-a));
        }
        float phi = ml_b3[0];
        #pragma unroll
        for (int k = 0; k < 16; ++k) phi = fmaf(h2[k], ml_W3[k], phi);
        const float sc = expf(phi - 0.25f * x);
        ws[WS_TBL + t] = sc;
        if (t < NBINS) out_bins[t] = sc;  // dl2_scores term of output 1
    }
}

// R1's proven 2-row MLP body, verbatim (scalar fmaf, SGPR weights,
// fence every 2 weight rows).  Factored so the two-leg pipeline below
// can run it twice without code drift.
static __device__ __forceinline__ void mlp_pair(
        const float* __restrict__ ws,
        const float (&xf0)[8], const float (&xf1)[8],
        int dlx, int dly, float& sc0, float& sc1) {
    // ---- layer 1: 8 -> 16 (weights prescaled by -log2e) ----
    float u0[16], u1[16];
    #pragma unroll
    for (int j = 0; j < 16; ++j) {
        const float b = ws[WS_B1 + j];
        u0[j] = b; u1[j] = b;
    }
    SCHED_FENCE();
    #pragma unroll
    for (int f = 0; f < 8; ++f) {
        #pragma unroll
        for (int j = 0; j < 16; ++j) {
            const float w = ws[WS_W1 + f * 16 + j];
            u0[j] = fmaf(xf0[f], w, u0[j]);
            u1[j] = fmaf(xf1[f], w, u1[j]);
        }
        if (f & 1) SCHED_FENCE();
    }
    float h0[16], h1[16];
    #pragma unroll
    for (int j = 0; j < 16; ++j) {
        h0[j] = RCPF(1.0f + EXP2F(u0[j]));
        h1[j] = RCPF(1.0f + EXP2F(u1[j]));
    }

    // ---- layer 2: 16 -> 16 ----
    float v0[16], v1[16];
    #pragma unroll
    for (int j = 0; j < 16; ++j) {
        const float b = ws[WS_B2 + j];
        v0[j] = b; v1[j] = b;
    }
    SCHED_FENCE();
    #pragma unroll
    for (int k = 0; k < 16; ++k) {
        #pragma unroll
        for (int j = 0; j < 16; ++j) {
            const float w = ws[WS_W2 + k * 16 + j];
            v0[j] = fmaf(h0[k], w, v0[j]);
            v1[j] = fmaf(h1[k], w, v1[j]);
        }
        if (k & 1) SCHED_FENCE();
    }

    // ---- layer 3 + psi ----
    float phi0 = ws[WS_B3], phi1 = phi0;   // prescaled by +log2e
    #pragma unroll
    for (int j = 0; j < 16; ++j) {
        const float w3 = ws[WS_W3 + j];    // prescaled by +log2e
        phi0 = fmaf(RCPF(1.0f + EXP2F(v0[j])), w3, phi0);
        phi1 = fmaf(RCPF(1.0f + EXP2F(v1[j])), w3, phi1);
    }
    sc0 = EXP2F(fmaf((float)dlx, -0.25f * L2E, phi0));
    sc1 = EXP2F(fmaf((float)dly, -0.25f * L2E, phi1));
}

// Two-leg software pipeline: each thread handles 2 pairs (4 rows).
// ALL of leg B's global loads are issued before leg A's compute (and
// before the first sched_barrier, so they cannot sink); B's vmcnt wait
// lands after ~2500 cycles of leg-A math -> B's memory latency is fully
// hidden, and per-row exposed entry latency halves.  R1 diagnosis: true
// per-SIMD VALU issue occupancy was ~24% (VALUBusy 77% is any-of-4-SIMD)
// -> the kernel is latency-bound on wave-entry loads, not issue-bound.
__global__ __launch_bounds__(256) void main_kernel(
        const float4* __restrict__ x4,
        const int2* __restrict__ dl2p,
        const int2* __restrict__ ml2p,
        const float* __restrict__ ws,
        float2* __restrict__ out2,
        float* __restrict__ out_bins,
        int npair, int G) {
    __shared__ float s_tbl[40];
    __shared__ float s_bins[4 * NBINS];
    const int tid = threadIdx.x;
    if (tid < 40) s_tbl[tid] = ws[WS_TBL + tid];
    if (tid < 4 * NBINS) s_bins[tid] = 0.0f;
    __syncthreads();

    const int pA = blockIdx.x * 256 + tid;
    const int pB = pA + G;
    const bool actA = (pA < npair);
    const bool actB = (pB < npair);
    const int pcA = actA ? pA : 0;
    const int pcB = actB ? pB : 0;

    // ---- issue ALL global loads up front (A then B) ----
    const float4 Aa0 = x4[4 * pcA + 0];
    const float4 Aa1 = x4[4 * pcA + 1];
    const float4 Ab0 = x4[4 * pcA + 2];
    const float4 Ab1 = x4[4 * pcA + 3];
    const int2 dlA = dl2p[pcA];
    const int2 mlA = ml2p[pcA];
    const float4 Ba0 = x4[4 * pcB + 0];
    const float4 Ba1 = x4[4 * pcB + 1];
    const float4 Bb0 = x4[4 * pcB + 2];
    const float4 Bb1 = x4[4 * pcB + 3];
    const int2 dlB = dl2p[pcB];
    const int2 mlB = ml2p[pcB];

    float* myb = &s_bins[(tid >> 6) * NBINS];

    // ---- leg A ----
    {
        const float xf0[8] = {Aa0.x, Aa0.y, Aa0.z, Aa0.w, Aa1.x, Aa1.y, Aa1.z, Aa1.w};
        const float xf1[8] = {Ab0.x, Ab0.y, Ab0.z, Ab0.w, Ab1.x, Ab1.y, Ab1.z, Ab1.w};
        float sc0, sc1;
        mlp_pair(ws, xf0, xf1, dlA.x, dlA.y, sc0, sc1);
        if (actA) {
            const int i0 = min(max(dlA.x, 1), 40) - 1;
            const int i1 = min(max(dlA.y, 1), 40) - 1;
            const float add0 = (dlA.x == mlA.x) ? s_tbl[i0] : 0.0f;
            const float add1 = (dlA.y == mlA.y) ? s_tbl[i1] : 0.0f;
            out2[pA] = make_float2(sc0 + add0, sc1 + add1);
            if (dlA.x >= 1 && dlA.x <= NBINS) unsafeAtomicAdd(&myb[dlA.x - 1], sc0);
            if (dlA.y >= 1 && dlA.y <= NBINS) unsafeAtomicAdd(&myb[dlA.y - 1], sc1);
        }
    }

    // ---- leg B (loads long since in flight; waitcnt lands here) ----
    {
        const float xf0[8] = {Ba0.x, Ba0.y, Ba0.z, Ba0.w, Ba1.x, Ba1.y, Ba1.z, Ba1.w};
        const float xf1[8] = {Bb0.x, Bb0.y, Bb0.z, Bb0.w, Bb1.x, Bb1.y, Bb1.z, Bb1.w};
        float sc0, sc1;
        mlp_pair(ws, xf0, xf1, dlB.x, dlB.y, sc0, sc1);
        if (actB) {
            const int i0 = min(max(dlB.x, 1), 40) - 1;
            const int i1 = min(max(dlB.y, 1), 40) - 1;
            const float add0 = (dlB.x == mlB.x) ? s_tbl[i0] : 0.0f;
            const float add1 = (dlB.y == mlB.y) ? s_tbl[i1] : 0.0f;
            out2[pB] = make_float2(sc0 + add0, sc1 + add1);
            if (dlB.x >= 1 && dlB.x <= NBINS) unsafeAtomicAdd(&myb[dlB.x - 1], sc0);
            if (dlB.y >= 1 && dlB.y <= NBINS) unsafeAtomicAdd(&myb[dlB.y - 1], sc1);
        }
    }

    __syncthreads();
    if (tid < NBINS) {
        const float bsum = s_bins[tid] + s_bins[NBINS + tid] +
                           s_bins[2 * NBINS + tid] + s_bins[3 * NBINS + tid];
        unsafeAtomicAdd(&out_bins[tid], bsum);
    }
}

extern "C" void kernel_launch(void* const* d_in, const int* in_sizes, int n_in,
                              void* d_out, int out_size, void* d_ws, size_t ws_size,
                              hipStream_t stream) {
    const int n = in_sizes[0] / 8;  // N rows (even)

    const float* x_feat = (const float*)d_in[0];
    const float* mh_W1  = (const float*)d_in[1];
    const float* mh_b1  = (const float*)d_in[2];
    const float* mh_W2  = (const float*)d_in[3];
    const float* mh_b2  = (const float*)d_in[4];
    const float* mh_W3  = (const float*)d_in[5];
    const float* mh_b3  = (const float*)d_in[6];
    const float* ml_W1  = (const float*)d_in[7];
    const float* ml_b1  = (const float*)d_in[8];
    const float* ml_W2  = (const float*)d_in[9];
    const float* ml_b2  = (const float*)d_in[10];
    const float* ml_W3  = (const float*)d_in[11];
    const float* ml_b3  = (const float*)d_in[12];
    const int* del_lens = (const int*)d_in[13];
    const int* mh_len   = (const int*)d_in[14];

    float* out      = (float*)d_out;
    float* out_bins = out + n;  // last 28 elements of d_out
    float* ws       = (float*)d_ws;

    prep_kernel<<<dim3(1), dim3(64), 0, stream>>>(
        mh_W1, mh_b1, mh_W2, mh_b2, mh_W3, mh_b3,
        ml_W1, ml_b1, ml_W2, ml_b2, ml_W3, ml_b3,
        ws, out_bins);

    const int npair = n / 2;
    const int nblocks = (npair + 511) / 512;   // 2 pairs per thread
    const int G = nblocks * 256;               // leg stride
    main_kernel<<<dim3(nblocks), dim3(256), 0, stream>>>(
        (const float4*)x_feat, (const int2*)del_lens, (const int2*)mh_len,
        ws, (float2*)out, out_bins, npair, G);
}